// Round 1
// baseline (66.700 us; speedup 1.0000x reference)
//
#include <hip/hip_runtime.h>
#include <float.h>

// Problem constants (from reference setup_inputs)
#define BB      2
#define CCH     256
#define HND     100
#define WND     100
#define NPTS    (HND * WND)   // 10000
#define NPOINT  9

// ---------------------------------------------------------------------------
// Kernel 1: transpose feat_map (B,C,H,W) -> (B,H*W,C) so channel reads are
// contiguous. Classic 32x32 LDS tile transpose. Rows = C (256), Cols = HW
// (10000). Grid: (ceil(HW/32), C/32, B), block (32,8).
// ---------------------------------------------------------------------------
__global__ __launch_bounds__(256)
void transpose_feat(const float* __restrict__ in, float* __restrict__ out) {
    __shared__ float tile[32][33];  // +1 pad: no LDS bank conflicts
    const int b    = blockIdx.z;
    const int col0 = blockIdx.x * 32;  // hw
    const int row0 = blockIdx.y * 32;  // c
    const int tx = threadIdx.x, ty = threadIdx.y;
    const float* src = in  + (size_t)b * CCH * NPTS;
    float*       dst = out + (size_t)b * NPTS * CCH;
#pragma unroll
    for (int i = 0; i < 4; ++i) {
        const int r   = row0 + ty + i * 8;   // channel (always < 256)
        const int col = col0 + tx;           // hw
        if (col < NPTS) tile[ty + i * 8][tx] = src[(size_t)r * NPTS + col];
    }
    __syncthreads();
#pragma unroll
    for (int i = 0; i < 4; ++i) {
        const int c2 = row0 + tx;            // channel
        const int hw = col0 + ty + i * 8;    // hw
        if (hw < NPTS) dst[(size_t)hw * CCH + c2] = tile[tx][ty + i * 8];
    }
}

// ---------------------------------------------------------------------------
// Kernel 2: deformable bilinear gather. One 64-lane wave per gather point
// (pid in [0, B*N*9)); lane handles 4 channels via float4. Block = 256 = 4
// waves = 4 points.
// ---------------------------------------------------------------------------
template <bool TRANSPOSED>
__global__ __launch_bounds__(256)
void deform_gather(const float* __restrict__ feat,       // TR ? (B,HW,C) : (B,C,H,W)
                   const float* __restrict__ locations,  // (N,3)
                   const float* __restrict__ offset,     // (B,N,9,2)
                   float* __restrict__ out)              // (B,N,9,C)
{
    const int wid  = threadIdx.x >> 6;
    const int lane = threadIdx.x & 63;
    const int pid  = blockIdx.x * 4 + wid;
    if (pid >= BB * NPTS * NPOINT) return;

    const int b   = pid / (NPTS * NPOINT);
    const int rem = pid - b * (NPTS * NPOINT);
    const int n   = rem / NPOINT;

    // index = (center + (offset*64)*0.1) / 8   (exact *0.125)
    const float cx = locations[n * 3 + 0];
    const float cy = locations[n * 3 + 1];
    const float ox = offset[(size_t)pid * 2 + 0];
    const float oy = offset[(size_t)pid * 2 + 1];
    const float w = (cx + (ox * 64.0f) * 0.1f) * 0.125f;
    const float h = (cy + (oy * 64.0f) * 0.1f) * 0.125f;

    // Reference boundary semantics (clamp-at-top, extrapolate-below).
    const float h_low = fminf(fmaxf(floorf(h), 0.0f), (float)(HND - 1));
    const float w_low = fminf(fmaxf(floorf(w), 0.0f), (float)(WND - 1));
    const bool  hcap = (h_low >= (float)(HND - 1));
    const bool  wcap = (w_low >= (float)(WND - 1));
    const float h_high = hcap ? h_low : h_low + 1.0f;
    const float w_high = wcap ? w_low : w_low + 1.0f;
    const float he = hcap ? h_low : h;
    const float we = wcap ? w_low : w;
    const int hl  = (int)h_low,  wl  = (int)w_low;
    const int hhi = (int)h_high, whi = (int)w_high;
    const float lh = he - h_low, lw = we - w_low;
    const float hh = 1.0f - lh,  hw = 1.0f - lw;
    const float w1 = hh * hw, w2 = hh * lw, w3 = lh * hw, w4 = lh * lw;

    float* o = out + (size_t)pid * CCH;

    if (TRANSPOSED) {
        const float* base = feat + (size_t)b * NPTS * CCH;
        const float4* p1 = (const float4*)(base + (size_t)(hl  * WND + wl ) * CCH);
        const float4* p2 = (const float4*)(base + (size_t)(hl  * WND + whi) * CCH);
        const float4* p3 = (const float4*)(base + (size_t)(hhi * WND + wl ) * CCH);
        const float4* p4 = (const float4*)(base + (size_t)(hhi * WND + whi) * CCH);
        const float4 a = p1[lane], bv = p2[lane], cv = p3[lane], dv = p4[lane];
        float4 r;
        r.x = w1 * a.x + w2 * bv.x + w3 * cv.x + w4 * dv.x;
        r.y = w1 * a.y + w2 * bv.y + w3 * cv.y + w4 * dv.y;
        r.z = w1 * a.z + w2 * bv.z + w3 * cv.z + w4 * dv.z;
        r.w = w1 * a.w + w2 * bv.w + w3 * cv.w + w4 * dv.w;
        ((float4*)o)[lane] = r;
    } else {
        // Fallback: original (B,C,H,W) layout, uncoalesced but correct.
        const float* base = feat + (size_t)b * CCH * NPTS;
        const int i1 = hl * WND + wl,  i2 = hl * WND + whi;
        const int i3 = hhi * WND + wl, i4 = hhi * WND + whi;
        for (int c = lane; c < CCH; c += 64) {
            const float* f = base + (size_t)c * NPTS;
            o[c] = w1 * f[i1] + w2 * f[i2] + w3 * f[i3] + w4 * f[i4];
        }
    }
}

// ---------------------------------------------------------------------------
// Kernel 3: regression boxes. One thread per (b,n).
// ---------------------------------------------------------------------------
__global__ __launch_bounds__(256)
void boxes_kernel(const float* __restrict__ locations,
                  const float* __restrict__ offset,    // (B,N,18)
                  const float* __restrict__ loc_pred,  // (B,N,18)
                  float* __restrict__ out)             // (B,N,4)
{
    const int idx = blockIdx.x * blockDim.x + threadIdx.x;
    if (idx >= BB * NPTS) return;
    const int n = idx % NPTS;

    const float cx = locations[n * 3 + 0];
    const float cy = locations[n * 3 + 1];
    const float scale_ = locations[n * 3 + 2] * 8.0f;  // BASE_SCALE

    const float* off = offset  + (size_t)idx * (NPOINT * 2);
    const float* lp  = loc_pred + (size_t)idx * (NPOINT * 2);

    float xmin = FLT_MAX, ymin = FLT_MAX, xmax = -FLT_MAX, ymax = -FLT_MAX;
#pragma unroll
    for (int k = 0; k < NPOINT; ++k) {
        const float px = (cx + (off[2 * k    ] * scale_) * 0.1f) + (lp[2 * k    ] * scale_) * 0.5f;
        const float py = (cy + (off[2 * k + 1] * scale_) * 0.1f) + (lp[2 * k + 1] * scale_) * 0.5f;
        xmin = fminf(xmin, px); xmax = fmaxf(xmax, px);
        ymin = fminf(ymin, py); ymax = fmaxf(ymax, py);
    }
    float* ob = out + (size_t)idx * 4;
    ob[0] = xmin; ob[1] = ymin; ob[2] = xmax; ob[3] = ymax;
}

// ---------------------------------------------------------------------------
extern "C" void kernel_launch(void* const* d_in, const int* in_sizes, int n_in,
                              void* d_out, int out_size, void* d_ws, size_t ws_size,
                              hipStream_t stream) {
    const float* feat      = (const float*)d_in[0];
    const float* locations = (const float*)d_in[1];
    const float* offset    = (const float*)d_in[2];
    const float* loc_pred  = (const float*)d_in[3];
    float* out = (float*)d_out;

    const size_t deform_elems = (size_t)BB * NPTS * NPOINT * CCH;
    const size_t need_ws = (size_t)BB * NPTS * CCH * sizeof(float);

    const int npoints = BB * NPTS * NPOINT;           // 180000
    const int gather_blocks = (npoints + 3) / 4;      // 4 waves/block, 1 pt/wave

    if (ws_size >= need_ws) {
        dim3 tg((NPTS + 31) / 32, CCH / 32, BB);
        transpose_feat<<<tg, dim3(32, 8), 0, stream>>>(feat, (float*)d_ws);
        deform_gather<true><<<gather_blocks, 256, 0, stream>>>(
            (const float*)d_ws, locations, offset, out);
    } else {
        deform_gather<false><<<gather_blocks, 256, 0, stream>>>(
            feat, locations, offset, out);
    }

    boxes_kernel<<<(BB * NPTS + 255) / 256, 256, 0, stream>>>(
        locations, offset, loc_pred, out + deform_elems);
}

// Round 3
// 62.622 us; speedup vs baseline: 1.0651x; 1.0651x over previous
//
#include <hip/hip_runtime.h>
#include <float.h>

// Problem constants (from reference setup_inputs)
#define BB      2
#define CCH     256
#define HND     100
#define WND     100
#define NPTS    (HND * WND)   // 10000
#define NPOINT  9
#define NPTOT   (BB * NPTS * NPOINT)   // 180000 gather points
#define NBOX    (BB * NPTS)            // 20000 boxes

// Gather grid geometry: 4 waves/block, 2 points/wave -> 8 points/block
#define GATHER_BLOCKS (NPTOT / 8)      // 22500 (exact)
#define BOX_BLOCKS    ((NBOX + 255) / 256)  // 79

// Native clang vector type — required by __builtin_nontemporal_store
typedef float f32x4 __attribute__((ext_vector_type(4)));

// ---------------------------------------------------------------------------
// Kernel 1: transpose feat_map (B,C,H,W) -> (B,H*W,C) so channel reads are
// contiguous. 32x32 LDS tile transpose, +1 pad (no bank conflicts).
// Grid: (ceil(HW/32), C/32, B), block (32,8).
// ---------------------------------------------------------------------------
__global__ __launch_bounds__(256)
void transpose_feat(const float* __restrict__ in, float* __restrict__ out) {
    __shared__ float tile[32][33];
    const int b    = blockIdx.z;
    const int col0 = blockIdx.x * 32;  // hw
    const int row0 = blockIdx.y * 32;  // c
    const int tx = threadIdx.x, ty = threadIdx.y;
    const float* src = in  + (size_t)b * CCH * NPTS;
    float*       dst = out + (size_t)b * NPTS * CCH;
#pragma unroll
    for (int i = 0; i < 4; ++i) {
        const int r   = row0 + ty + i * 8;   // channel (< 256 always)
        const int col = col0 + tx;           // hw
        if (col < NPTS) tile[ty + i * 8][tx] = src[(size_t)r * NPTS + col];
    }
    __syncthreads();
#pragma unroll
    for (int i = 0; i < 4; ++i) {
        const int c2 = row0 + tx;            // channel
        const int hw = col0 + ty + i * 8;    // hw
        if (hw < NPTS) dst[(size_t)hw * CCH + c2] = tile[tx][ty + i * 8];
    }
}

// ---------------------------------------------------------------------------
// Bilinear weights/corner computation with the reference's exact boundary
// semantics (clamp at top edge, extrapolate below 0).
// ---------------------------------------------------------------------------
struct Bilin {
    int i1, i2, i3, i4;      // hw indices of 4 corners
    float w1, w2, w3, w4;    // weights
};

__device__ __forceinline__ Bilin bilin_setup(float w, float h) {
    Bilin r;
    const float h_low = fminf(fmaxf(floorf(h), 0.0f), (float)(HND - 1));
    const float w_low = fminf(fmaxf(floorf(w), 0.0f), (float)(WND - 1));
    const bool  hcap = (h_low >= (float)(HND - 1));
    const bool  wcap = (w_low >= (float)(WND - 1));
    const float h_high = hcap ? h_low : h_low + 1.0f;
    const float w_high = wcap ? w_low : w_low + 1.0f;
    const float he = hcap ? h_low : h;
    const float we = wcap ? w_low : w;
    const int hl  = (int)h_low,  wl  = (int)w_low;
    const int hhi = (int)h_high, whi = (int)w_high;
    const float lh = he - h_low, lw = we - w_low;
    const float hh = 1.0f - lh,  hw = 1.0f - lw;
    r.w1 = hh * hw; r.w2 = hh * lw; r.w3 = lh * hw; r.w4 = lh * lw;
    r.i1 = hl * WND + wl;  r.i2 = hl * WND + whi;
    r.i3 = hhi * WND + wl; r.i4 = hhi * WND + whi;
    return r;
}

// ---------------------------------------------------------------------------
// Kernel 2: deformable bilinear gather + (fused, extra blocks) boxes.
// One 64-lane wave handles TWO gather points; lane = 4 channels (f32x4).
// Output stores are non-temporal: 184.6 MB write-once stream must not evict
// the 20.5 MB transposed feat from L2.
// ---------------------------------------------------------------------------
__global__ __launch_bounds__(256)
void deform_gather_boxes(const float* __restrict__ feat,       // (B,HW,C)
                         const float* __restrict__ locations,  // (N,3)
                         const float* __restrict__ offset,     // (B,N,9,2)
                         const float* __restrict__ loc_pred,   // (B,N,18)
                         float* __restrict__ out_feats,        // (B,N,9,C)
                         float* __restrict__ out_boxes)        // (B,N,4)
{
    if (blockIdx.x < GATHER_BLOCKS) {
        const int wid  = threadIdx.x >> 6;
        const int lane = threadIdx.x & 63;
        const int p0 = (blockIdx.x * 4 + wid) * 2;   // first of the 2 points
        const int p1 = p0 + 1;

        // --- point 0 address math ---
        const int b0 = p0 / (NPTS * NPOINT);
        const int n0 = (p0 - b0 * (NPTS * NPOINT)) / NPOINT;
        const float w0f = (locations[n0 * 3 + 0] + (offset[(size_t)p0 * 2 + 0] * 64.0f) * 0.1f) * 0.125f;
        const float h0f = (locations[n0 * 3 + 1] + (offset[(size_t)p0 * 2 + 1] * 64.0f) * 0.1f) * 0.125f;
        const Bilin s0 = bilin_setup(w0f, h0f);
        // --- point 1 address math ---
        const int b1 = p1 / (NPTS * NPOINT);
        const int n1 = (p1 - b1 * (NPTS * NPOINT)) / NPOINT;
        const float w1f = (locations[n1 * 3 + 0] + (offset[(size_t)p1 * 2 + 0] * 64.0f) * 0.1f) * 0.125f;
        const float h1f = (locations[n1 * 3 + 1] + (offset[(size_t)p1 * 2 + 1] * 64.0f) * 0.1f) * 0.125f;
        const Bilin s1 = bilin_setup(w1f, h1f);

        const float* base0 = feat + (size_t)b0 * NPTS * CCH;
        const float* base1 = feat + (size_t)b1 * NPTS * CCH;

        // Issue all 8 corner loads up front (8 outstanding vmem / wave).
        const f32x4 a0  = ((const f32x4*)(base0 + (size_t)s0.i1 * CCH))[lane];
        const f32x4 b0v = ((const f32x4*)(base0 + (size_t)s0.i2 * CCH))[lane];
        const f32x4 c0  = ((const f32x4*)(base0 + (size_t)s0.i3 * CCH))[lane];
        const f32x4 d0  = ((const f32x4*)(base0 + (size_t)s0.i4 * CCH))[lane];
        const f32x4 a1  = ((const f32x4*)(base1 + (size_t)s1.i1 * CCH))[lane];
        const f32x4 b1v = ((const f32x4*)(base1 + (size_t)s1.i2 * CCH))[lane];
        const f32x4 c1  = ((const f32x4*)(base1 + (size_t)s1.i3 * CCH))[lane];
        const f32x4 d1  = ((const f32x4*)(base1 + (size_t)s1.i4 * CCH))[lane];

        const f32x4 r0 = s0.w1 * a0 + s0.w2 * b0v + s0.w3 * c0 + s0.w4 * d0;
        const f32x4 r1 = s1.w1 * a1 + s1.w2 * b1v + s1.w3 * c1 + s1.w4 * d1;

        __builtin_nontemporal_store(r0, (f32x4*)(out_feats + (size_t)p0 * CCH) + lane);
        __builtin_nontemporal_store(r1, (f32x4*)(out_feats + (size_t)p1 * CCH) + lane);
    } else {
        // ----- boxes: one thread per (b,n) -----
        const int idx = (blockIdx.x - GATHER_BLOCKS) * 256 + threadIdx.x;
        if (idx >= NBOX) return;
        const int n = idx % NPTS;

        const float cx = locations[n * 3 + 0];
        const float cy = locations[n * 3 + 1];
        const float scale_ = locations[n * 3 + 2] * 8.0f;  // BASE_SCALE

        const float* off = offset   + (size_t)idx * (NPOINT * 2);
        const float* lp  = loc_pred + (size_t)idx * (NPOINT * 2);

        float xmin = FLT_MAX, ymin = FLT_MAX, xmax = -FLT_MAX, ymax = -FLT_MAX;
#pragma unroll
        for (int k = 0; k < NPOINT; ++k) {
            const float px = (cx + (off[2 * k    ] * scale_) * 0.1f) + (lp[2 * k    ] * scale_) * 0.5f;
            const float py = (cy + (off[2 * k + 1] * scale_) * 0.1f) + (lp[2 * k + 1] * scale_) * 0.5f;
            xmin = fminf(xmin, px); xmax = fmaxf(xmax, px);
            ymin = fminf(ymin, py); ymax = fmaxf(ymax, py);
        }
        f32x4 bx = { xmin, ymin, xmax, ymax };
        __builtin_nontemporal_store(bx, (f32x4*)(out_boxes + (size_t)idx * 4));
    }
}

// ---------------------------------------------------------------------------
// Fallback gather for the case ws is too small (keeps original layout).
// ---------------------------------------------------------------------------
__global__ __launch_bounds__(256)
void deform_gather_direct(const float* __restrict__ feat,       // (B,C,H,W)
                          const float* __restrict__ locations,
                          const float* __restrict__ offset,
                          float* __restrict__ out)
{
    const int wid  = threadIdx.x >> 6;
    const int lane = threadIdx.x & 63;
    const int pid  = blockIdx.x * 4 + wid;
    if (pid >= NPTOT) return;
    const int b   = pid / (NPTS * NPOINT);
    const int n   = (pid - b * (NPTS * NPOINT)) / NPOINT;
    const float w = (locations[n * 3 + 0] + (offset[(size_t)pid * 2 + 0] * 64.0f) * 0.1f) * 0.125f;
    const float h = (locations[n * 3 + 1] + (offset[(size_t)pid * 2 + 1] * 64.0f) * 0.1f) * 0.125f;
    const Bilin s = bilin_setup(w, h);
    const float* base = feat + (size_t)b * CCH * NPTS;
    float* o = out + (size_t)pid * CCH;
    for (int c = lane; c < CCH; c += 64) {
        const float* f = base + (size_t)c * NPTS;
        o[c] = s.w1 * f[s.i1] + s.w2 * f[s.i2] + s.w3 * f[s.i3] + s.w4 * f[s.i4];
    }
}

__global__ __launch_bounds__(256)
void boxes_kernel(const float* __restrict__ locations,
                  const float* __restrict__ offset,
                  const float* __restrict__ loc_pred,
                  float* __restrict__ out)
{
    const int idx = blockIdx.x * blockDim.x + threadIdx.x;
    if (idx >= NBOX) return;
    const int n = idx % NPTS;
    const float cx = locations[n * 3 + 0];
    const float cy = locations[n * 3 + 1];
    const float scale_ = locations[n * 3 + 2] * 8.0f;
    const float* off = offset   + (size_t)idx * (NPOINT * 2);
    const float* lp  = loc_pred + (size_t)idx * (NPOINT * 2);
    float xmin = FLT_MAX, ymin = FLT_MAX, xmax = -FLT_MAX, ymax = -FLT_MAX;
#pragma unroll
    for (int k = 0; k < NPOINT; ++k) {
        const float px = (cx + (off[2 * k    ] * scale_) * 0.1f) + (lp[2 * k    ] * scale_) * 0.5f;
        const float py = (cy + (off[2 * k + 1] * scale_) * 0.1f) + (lp[2 * k + 1] * scale_) * 0.5f;
        xmin = fminf(xmin, px); xmax = fmaxf(xmax, px);
        ymin = fminf(ymin, py); ymax = fmaxf(ymax, py);
    }
    float* ob = out + (size_t)idx * 4;
    ob[0] = xmin; ob[1] = ymin; ob[2] = xmax; ob[3] = ymax;
}

// ---------------------------------------------------------------------------
extern "C" void kernel_launch(void* const* d_in, const int* in_sizes, int n_in,
                              void* d_out, int out_size, void* d_ws, size_t ws_size,
                              hipStream_t stream) {
    const float* feat      = (const float*)d_in[0];
    const float* locations = (const float*)d_in[1];
    const float* offset    = (const float*)d_in[2];
    const float* loc_pred  = (const float*)d_in[3];
    float* out = (float*)d_out;

    const size_t deform_elems = (size_t)NPTOT * CCH;
    const size_t need_ws = (size_t)BB * NPTS * CCH * sizeof(float);

    if (ws_size >= need_ws) {
        dim3 tg((NPTS + 31) / 32, CCH / 32, BB);
        transpose_feat<<<tg, dim3(32, 8), 0, stream>>>(feat, (float*)d_ws);
        deform_gather_boxes<<<GATHER_BLOCKS + BOX_BLOCKS, 256, 0, stream>>>(
            (const float*)d_ws, locations, offset, loc_pred,
            out, out + deform_elems);
    } else {
        deform_gather_direct<<<(NPTOT + 3) / 4, 256, 0, stream>>>(
            feat, locations, offset, out);
        boxes_kernel<<<(NBOX + 255) / 256, 256, 0, stream>>>(
            locations, offset, loc_pred, out + deform_elems);
    }
}